// Round 17
// baseline (66.177 us; speedup 1.0000x reference)
//
#include <hip/hip_runtime.h>
#include <hip/hip_bf16.h>

// (B,L,H,E,D) = (2,2048,8,64,64); E==D==64.
namespace {
constexpr int Lc = 2048, Hc = 8;
constexpr int RS = Hc * 64;          // floats between consecutive l (=512)
constexpr int NKT = 32;              // 2048/64 kt tiles
constexpr int TILE_BYTES = 16384;    // K frags 8KB + V frags 8KB per (bh,kt)
constexpr int OUT4 = 2 * Lc * Hc * 64 / 4;
}

typedef __attribute__((ext_vector_type(8))) short bf16x8;
typedef __attribute__((ext_vector_type(16))) float f32x16;
typedef unsigned int u32;
typedef __attribute__((ext_vector_type(4))) u32 u32x4;

__device__ __forceinline__ short f2bf(float x) {
    return (short)__builtin_bit_cast(unsigned short, __float2bfloat16(x));
}

#define MFMA32(a, b, c) __builtin_amdgcn_mfma_f32_32x32x16_bf16((a), (b), (c), 0, 0, 0)

__global__ __launch_bounds__(256) void zero_out(float4* __restrict__ o) {
    const int i = blockIdx.x * 256 + threadIdx.x;
    if (i < OUT4) o[i] = make_float4(0.f, 0.f, 0.f, 0.f);
}

// ------------- prep: f32 K,V -> bf16 32x32x16-fragment-ordered tiles in ws -------------
// (unchanged — validated rounds 7-14)
__global__ __launch_bounds__(256)
void prep_kv(const float* __restrict__ kg, const float* __restrict__ vg,
             short* __restrict__ ws)
{
    const int kt = blockIdx.x, bh = blockIdx.y;
    const int b = bh >> 3, h = bh & 7;
    const size_t base = ((size_t)b * Lc * Hc + h) * 64;
    char* tile = (char*)ws + (size_t)(bh * NKT + kt) * TILE_BYTES;
    const int tid = threadIdx.x;

    {   // K A-frags
        const int c = tid & 7, e0 = c * 8;
        #pragma unroll
        for (int p = 0; p < 2; ++p) {
            const int s = (tid >> 3) + 32 * p;
            const float* src = kg + base + (size_t)(kt * 64 + s) * RS + e0;
            float4 x0 = *(const float4*)src;
            float4 x1 = *(const float4*)(src + 4);
            bf16x8 w = { f2bf(x0.x), f2bf(x0.y), f2bf(x0.z), f2bf(x0.w),
                         f2bf(x1.x), f2bf(x1.y), f2bf(x1.z), f2bf(x1.w) };
            const int lane = (c & 1) * 32 + (s & 31);
            const int byte = ((s >> 5) * 4 + (c >> 1)) * 1024 + lane * 16;
            *(bf16x8*)(tile + byte) = w;
        }
    }
    {   // V B-frags
        const int d = tid & 63;
        #pragma unroll
        for (int p = 0; p < 2; ++p) {
            const int sblk = (tid >> 6) + 4 * p;
            const int s0 = sblk * 8;
            float xv[8];
            #pragma unroll
            for (int j = 0; j < 8; ++j)
                xv[j] = vg[base + (size_t)(kt * 64 + s0 + j) * RS + d];
            bf16x8 w = { f2bf(xv[0]), f2bf(xv[1]), f2bf(xv[2]), f2bf(xv[3]),
                         f2bf(xv[4]), f2bf(xv[5]), f2bf(xv[6]), f2bf(xv[7]) };
            const int lane = (sblk & 1) * 32 + (d & 31);
            const int byte = 8192 + ((d >> 5) * 4 + (sblk >> 1)) * 1024 + lane * 16;
            *(bf16x8*)(tile + byte) = w;
        }
    }
}

// ---- attention: 1-wave blocks, Nq=2 (64 q-rows), kt-quartered strips, no LDS,
// ---- no barriers; K/V frags streamed L2->regs; atomic fused u-gate epilogue.
__global__ __launch_bounds__(64)
void gate_attn(const float* __restrict__ ug, const float* __restrict__ qg,
               const short* __restrict__ ws, float* __restrict__ outg)
{
    const int gid = (int)blockIdx.x;
    const int xcd = gid & 7;                 // XCD-local bh pair
    const int uu = gid >> 3;                 // 0..255 per XCD
    const int ktq = uu & 3;                  // kt quarter
    const int z = uu >> 2;                   // 0..63
    const int sr = z & 31, bh_bit = z >> 5;
    const int strip = (sr & 1) ? (31 - (sr >> 1)) : (sr >> 1);  // heavy/light alternating
    const int bh = 2 * xcd + bh_bit;

    const int kt0 = ktq * 8;
    if (kt0 > strip) return;                 // inactive quarter
    const int kt1 = min(kt0 + 8, strip + 1);

    const int lane = threadIdx.x;
    const int col = lane & 31, hi = lane >> 5;
    const int b = bh >> 3, h = bh & 7;
    const size_t base = ((size_t)b * Lc * Hc + h) * 64;
    const char* wsbh = (const char*)ws + (size_t)bh * NKT * TILE_BYTES;

    // ---- Q B-frags for 2 q-blocks (64 rows), once per wave ----
    bf16x8 qf[2][4];
    #pragma unroll
    for (int q2 = 0; q2 < 2; ++q2)
        #pragma unroll
        for (int es = 0; es < 4; ++es) {
            const float* p = qg + base +
                (size_t)(strip * 64 + q2 * 32 + col) * RS + es * 16 + hi * 8;
            float4 a = *(const float4*)p;
            float4 c2 = *(const float4*)(p + 4);
            qf[q2][es] = (bf16x8){ f2bf(a.x),  f2bf(a.y),  f2bf(a.z),  f2bf(a.w),
                                   f2bf(c2.x), f2bf(c2.y), f2bf(c2.z), f2bf(c2.w) };
        }

    f32x16 oacc[2][2];                       // [q2][dh]
    #pragma unroll
    for (int q2 = 0; q2 < 2; ++q2)
        #pragma unroll
        for (int r = 0; r < 16; ++r) { oacc[q2][0][r] = 0.f; oacc[q2][1][r] = 0.f; }

    for (int kt = kt0; kt < kt1; ++kt) {
        const char* kb = wsbh + (size_t)kt * TILE_BYTES + lane * 16;

        // ---- V frags to regs early (independent; latency hides under QK) ----
        const char* vb = kb + 8192;
        bf16x8 vf[2][4];
        #pragma unroll
        for (int dh = 0; dh < 2; ++dh)
            #pragma unroll
            for (int ks = 0; ks < 4; ++ks)
                vf[dh][ks] = *(const bf16x8*)(vb + (dh * 4 + ks) * 1024);

        const bool dmask = (kt == strip);
        u32 pa[2][4][4];                     // [q2][ks][word]

        #pragma unroll
        for (int sb = 0; sb < 2; ++sb) {
            // ---- swapped QK^T: each kf feeds 2 MFMAs (Nq=2) ----
            f32x16 sacc0 = (f32x16)(0.f), sacc1 = (f32x16)(0.f);
            #pragma unroll
            for (int es = 0; es < 4; ++es) {
                bf16x8 kf = *(const bf16x8*)(kb + (sb * 4 + es) * 1024);
                sacc0 = MFMA32(kf, qf[0][es], sacc0);
                sacc1 = MFMA32(kf, qf[1][es], sacc1);
            }
            // ---- relu^2 + mask; cvt_pk pack; permlane -> PA frags (r7 path) ----
            #pragma unroll
            for (int q2 = 0; q2 < 2; ++q2) {
                const f32x16& sv = q2 ? sacc1 : sacc0;
                const int qg2 = strip * 64 + q2 * 32 + col;
                float pv[16];
                #pragma unroll
                for (int r = 0; r < 16; ++r) {
                    float x = sv[r];
                    x = (x > 0.f) ? x * x : 0.f;
                    const int s_g = kt * 64 + sb * 32 + (r & 3) + 8 * (r >> 2) + 4 * hi;
                    if (dmask && s_g > qg2) x = 0.f;
                    pv[r] = x;
                }
                u32 W[8];
                #pragma unroll
                for (int t = 0; t < 8; ++t)
                    asm("v_cvt_pk_bf16_f32 %0, %1, %2"
                        : "=v"(W[t]) : "v"(pv[2 * t]), "v"(pv[2 * t + 1]));
                asm volatile("v_permlane32_swap_b32 %0, %1" : "+v"(W[0]), "+v"(W[2]));
                asm volatile("v_permlane32_swap_b32 %0, %1" : "+v"(W[1]), "+v"(W[3]));
                asm volatile("v_permlane32_swap_b32 %0, %1" : "+v"(W[4]), "+v"(W[6]));
                asm volatile("v_permlane32_swap_b32 %0, %1" : "+v"(W[5]), "+v"(W[7]));
                pa[q2][sb * 2 + 0][0] = W[0]; pa[q2][sb * 2 + 0][1] = W[1];
                pa[q2][sb * 2 + 0][2] = W[2]; pa[q2][sb * 2 + 0][3] = W[3];
                pa[q2][sb * 2 + 1][0] = W[4]; pa[q2][sb * 2 + 1][1] = W[5];
                pa[q2][sb * 2 + 1][2] = W[6]; pa[q2][sb * 2 + 1][3] = W[7];
            }
        }

        // ---- PV: all operands in regs ----
        #pragma unroll
        for (int dh = 0; dh < 2; ++dh)
            #pragma unroll
            for (int ks = 0; ks < 4; ++ks) {
                u32x4 p0 = { pa[0][ks][0], pa[0][ks][1], pa[0][ks][2], pa[0][ks][3] };
                u32x4 p1 = { pa[1][ks][0], pa[1][ks][1], pa[1][ks][2], pa[1][ks][3] };
                oacc[0][dh] = MFMA32(__builtin_bit_cast(bf16x8, p0), vf[dh][ks], oacc[0][dh]);
                oacc[1][dh] = MFMA32(__builtin_bit_cast(bf16x8, p1), vf[dh][ks], oacc[1][dh]);
            }
    }

    // ---- fused epilogue: atomicAdd(u * sc * partial) [r10-validated numerics] ----
    const float sc = 1.0f / (64.0f * 2048.0f);   // exact pow2
    #pragma unroll
    for (int q2 = 0; q2 < 2; ++q2)
        #pragma unroll
        for (int dh = 0; dh < 2; ++dh)
            #pragma unroll
            for (int r = 0; r < 16; ++r) {
                const int m = q2 * 32 + (r & 3) + 8 * (r >> 2) + 4 * hi;
                const size_t idx = base + (size_t)(strip * 64 + m) * RS + dh * 32 + col;
                atomicAdd(&outg[idx], ug[idx] * oacc[q2][dh][r] * sc);
            }
}

extern "C" void kernel_launch(void* const* d_in, const int* in_sizes, int n_in,
                              void* d_out, int out_size, void* d_ws, size_t ws_size,
                              hipStream_t stream) {
    const float* u = (const float*)d_in[0];
    const float* q = (const float*)d_in[1];
    const float* k = (const float*)d_in[2];
    const float* v = (const float*)d_in[3];
    // d_in[4] (mask) is strict-upper-triangular; implemented analytically.
    float* out = (float*)d_out;

    zero_out<<<dim3((OUT4 + 255) / 256), dim3(256), 0, stream>>>((float4*)out);
    prep_kv<<<dim3(NKT, 16), dim3(256), 0, stream>>>(k, v, (short*)d_ws);
    gate_attn<<<dim3(2048), dim3(64), 0, stream>>>(u, q, (const short*)d_ws, out);
}

// Round 18
// 65.914 us; speedup vs baseline: 1.0040x; 1.0040x over previous
//
#include <hip/hip_runtime.h>
#include <hip/hip_bf16.h>

// (B,L,H,E,D) = (2,2048,8,64,64); E==D==64.
namespace {
constexpr int Lc = 2048, Hc = 8;
constexpr int RS = Hc * 64;          // floats between consecutive l (=512)
constexpr int NKT = 32;              // 2048/64 kt tiles
constexpr int TILE_BYTES = 16384;    // K frags 8KB + V frags 8KB per (bh,kt)
constexpr int OUT4 = 2 * Lc * Hc * 64 / 4;
}

typedef __attribute__((ext_vector_type(8))) short bf16x8;
typedef __attribute__((ext_vector_type(16))) float f32x16;
typedef unsigned int u32;
typedef __attribute__((ext_vector_type(4))) u32 u32x4;

__device__ __forceinline__ short f2bf(float x) {
    return (short)__builtin_bit_cast(unsigned short, __float2bfloat16(x));
}

#define MFMA32(a, b, c) __builtin_amdgcn_mfma_f32_32x32x16_bf16((a), (b), (c), 0, 0, 0)

#define GLL16(gp, lp) __builtin_amdgcn_global_load_lds( \
    (const __attribute__((address_space(1))) unsigned int*)(gp), \
    (__attribute__((address_space(3))) unsigned int*)(lp), 16, 0, 0)

__global__ __launch_bounds__(256) void zero_out(float4* __restrict__ o) {
    const int i = blockIdx.x * 256 + threadIdx.x;
    if (i < OUT4) o[i] = make_float4(0.f, 0.f, 0.f, 0.f);
}

// ------------- prep: f32 K,V -> bf16 32x32x16-fragment-ordered tiles in ws -------------
// (unchanged — validated rounds 7-17)
__global__ __launch_bounds__(256)
void prep_kv(const float* __restrict__ kg, const float* __restrict__ vg,
             short* __restrict__ ws)
{
    const int kt = blockIdx.x, bh = blockIdx.y;
    const int b = bh >> 3, h = bh & 7;
    const size_t base = ((size_t)b * Lc * Hc + h) * 64;
    char* tile = (char*)ws + (size_t)(bh * NKT + kt) * TILE_BYTES;
    const int tid = threadIdx.x;

    {   // K A-frags
        const int c = tid & 7, e0 = c * 8;
        #pragma unroll
        for (int p = 0; p < 2; ++p) {
            const int s = (tid >> 3) + 32 * p;
            const float* src = kg + base + (size_t)(kt * 64 + s) * RS + e0;
            float4 x0 = *(const float4*)src;
            float4 x1 = *(const float4*)(src + 4);
            bf16x8 w = { f2bf(x0.x), f2bf(x0.y), f2bf(x0.z), f2bf(x0.w),
                         f2bf(x1.x), f2bf(x1.y), f2bf(x1.z), f2bf(x1.w) };
            const int lane = (c & 1) * 32 + (s & 31);
            const int byte = ((s >> 5) * 4 + (c >> 1)) * 1024 + lane * 16;
            *(bf16x8*)(tile + byte) = w;
        }
    }
    {   // V B-frags
        const int d = tid & 63;
        #pragma unroll
        for (int p = 0; p < 2; ++p) {
            const int sblk = (tid >> 6) + 4 * p;
            const int s0 = sblk * 8;
            float xv[8];
            #pragma unroll
            for (int j = 0; j < 8; ++j)
                xv[j] = vg[base + (size_t)(kt * 64 + s0 + j) * RS + d];
            bf16x8 w = { f2bf(xv[0]), f2bf(xv[1]), f2bf(xv[2]), f2bf(xv[3]),
                         f2bf(xv[4]), f2bf(xv[5]), f2bf(xv[6]), f2bf(xv[7]) };
            const int lane = (sblk & 1) * 32 + (d & 31);
            const int byte = 8192 + ((d >> 5) * 4 + (sblk >> 1)) * 1024 + lane * 16;
            *(bf16x8*)(tile + byte) = w;
        }
    }
}

// ---- attention: 2-wave blocks (qs split), <=8-tile kt-chunks (uniform duration),
// ---- K+V staged LDS (r9 path), ~4 blocks/CU via backfill, atomic u-gate fold.
__global__ __launch_bounds__(128, 2)
void gate_attn(const float* __restrict__ ug, const float* __restrict__ qg,
               const short* __restrict__ ws, float* __restrict__ outg)
{
    __shared__ __align__(16) char lds[2][TILE_BYTES];   // 32KB double-buffer

    const int tid = threadIdx.x;
    const int qs = tid >> 6, lane = tid & 63;
    const int col = lane & 31, hi = lane >> 5;

    // block -> (xcd-local bh, strip, kt-chunk), heavy strips first
    const int i = (int)blockIdx.x;
    const int xcd = i & 7;
    const int j = i >> 3;                 // 0..159
    const int bh_bit = j & 1;
    const int c = j >> 1;                 // 0..79 chunk index (strips desc)
    int strip = 0, k0 = 0, k1 = 0;
    {
        int acc = 0;
        for (int s = 31; s >= 0; --s) {
            const int cc = (s + 8) >> 3;              // ceil((s+1)/8) chunks
            if (c < acc + cc) {
                strip = s;
                const int ci = c - acc;
                const int per = (s + cc) / cc;        // ceil((s+1)/cc)
                k0 = ci * per;
                k1 = min(k0 + per - 1, s);
                break;
            }
            acc += cc;
        }
    }
    const int bh = 2 * xcd + bh_bit;
    const int b = bh >> 3, h = bh & 7;
    const size_t base = ((size_t)b * Lc * Hc + h) * 64;
    const char* wsbh = (const char*)ws + (size_t)bh * NKT * TILE_BYTES;

    const int qw = strip * 64 + qs * 32;
    const int qg_l = qw + col;

    // ---- Q B-fragments (r9-validated) ----
    bf16x8 qf[4];
    #pragma unroll
    for (int es = 0; es < 4; ++es) {
        const float* p = qg + base + (size_t)(qw + col) * RS + es * 16 + hi * 8;
        float4 a = *(const float4*)p;
        float4 c2 = *(const float4*)(p + 4);
        qf[es] = (bf16x8){ f2bf(a.x),  f2bf(a.y),  f2bf(a.z),  f2bf(a.w),
                           f2bf(c2.x), f2bf(c2.y), f2bf(c2.z), f2bf(c2.w) };
    }

    auto STAGE = [&](int t, int buf) {    // full 16KB tile, 8 GLL16/thread
        const char* src = wsbh + (size_t)t * TILE_BYTES + tid * 16;
        char* dst = &lds[buf][0] + tid * 16;
        #pragma unroll
        for (int ii = 0; ii < 8; ++ii)
            GLL16(src + ii * 2048, dst + ii * 2048);
    };

    f32x16 oacc[2];
    #pragma unroll
    for (int r = 0; r < 16; ++r) { oacc[0][r] = 0.f; oacc[1][r] = 0.f; }

    STAGE(k0, 0);
    __syncthreads();

    for (int kt = k0; kt <= k1; ++kt) {
        const int buf = (kt - k0) & 1;
        if (kt < k1) STAGE(kt + 1, buf ^ 1);
        const char* kb = &lds[buf][0];

        // ---- swapped QK^T (validated r7/r9 path) ----
        f32x16 sacc[2];
        #pragma unroll
        for (int r = 0; r < 16; ++r) { sacc[0][r] = 0.f; sacc[1][r] = 0.f; }
        __builtin_amdgcn_s_setprio(1);
        #pragma unroll
        for (int sb = 0; sb < 2; ++sb)
            #pragma unroll
            for (int es = 0; es < 4; ++es) {
                bf16x8 kf = *(const bf16x8*)(kb + (sb * 4 + es) * 1024 + lane * 16);
                sacc[sb] = MFMA32(kf, qf[es], sacc[sb]);
            }
        __builtin_amdgcn_s_setprio(0);

        // ---- relu^2 + mask; cvt_pk pack; permlane -> PA frags ----
        const bool dmask = (kt == strip);
        u32 pa[4][4];
        #pragma unroll
        for (int sb = 0; sb < 2; ++sb) {
            float pv[16];
            #pragma unroll
            for (int r = 0; r < 16; ++r) {
                float x2 = sacc[sb][r];
                x2 = (x2 > 0.f) ? x2 * x2 : 0.f;
                const int s_g = kt * 64 + sb * 32 + (r & 3) + 8 * (r >> 2) + 4 * hi;
                if (dmask && s_g > qg_l) x2 = 0.f;
                pv[r] = x2;
            }
            u32 W[8];
            #pragma unroll
            for (int t = 0; t < 8; ++t)
                asm("v_cvt_pk_bf16_f32 %0, %1, %2"
                    : "=v"(W[t]) : "v"(pv[2 * t]), "v"(pv[2 * t + 1]));
            asm volatile("v_permlane32_swap_b32 %0, %1" : "+v"(W[0]), "+v"(W[2]));
            asm volatile("v_permlane32_swap_b32 %0, %1" : "+v"(W[1]), "+v"(W[3]));
            asm volatile("v_permlane32_swap_b32 %0, %1" : "+v"(W[4]), "+v"(W[6]));
            asm volatile("v_permlane32_swap_b32 %0, %1" : "+v"(W[5]), "+v"(W[7]));
            pa[sb * 2 + 0][0] = W[0]; pa[sb * 2 + 0][1] = W[1];
            pa[sb * 2 + 0][2] = W[2]; pa[sb * 2 + 0][3] = W[3];
            pa[sb * 2 + 1][0] = W[4]; pa[sb * 2 + 1][1] = W[5];
            pa[sb * 2 + 1][2] = W[6]; pa[sb * 2 + 1][3] = W[7];
        }

        // ---- PV from LDS V-frags ----
        const char* vb = kb + 8192;
        __builtin_amdgcn_s_setprio(1);
        #pragma unroll
        for (int dh = 0; dh < 2; ++dh)
            #pragma unroll
            for (int ks = 0; ks < 4; ++ks) {
                bf16x8 vf = *(const bf16x8*)(vb + (dh * 4 + ks) * 1024 + lane * 16);
                u32x4 pw = { pa[ks][0], pa[ks][1], pa[ks][2], pa[ks][3] };
                oacc[dh] = MFMA32(__builtin_bit_cast(bf16x8, pw), vf, oacc[dh]);
            }
        __builtin_amdgcn_s_setprio(0);

        __syncthreads();
    }

    // ---- fused epilogue: atomicAdd(u * sc * partial), <=4 adds/element ----
    const float sc = 1.0f / (64.0f * 2048.0f);   // exact pow2
    #pragma unroll
    for (int dh = 0; dh < 2; ++dh)
        #pragma unroll
        for (int r = 0; r < 16; ++r) {
            const int m = (r & 3) + 8 * (r >> 2) + 4 * hi;
            const size_t idx = base + (size_t)(qw + m) * RS + dh * 32 + col;
            atomicAdd(&outg[idx], ug[idx] * oacc[dh][r] * sc);
        }
}

extern "C" void kernel_launch(void* const* d_in, const int* in_sizes, int n_in,
                              void* d_out, int out_size, void* d_ws, size_t ws_size,
                              hipStream_t stream) {
    const float* u = (const float*)d_in[0];
    const float* q = (const float*)d_in[1];
    const float* k = (const float*)d_in[2];
    const float* v = (const float*)d_in[3];
    // d_in[4] (mask) is strict-upper-triangular; implemented analytically.
    float* out = (float*)d_out;

    zero_out<<<dim3((OUT4 + 255) / 256), dim3(256), 0, stream>>>((float4*)out);
    prep_kv<<<dim3(NKT, 16), dim3(256), 0, stream>>>(k, v, (short*)d_ws);
    // 8 xcd x 2 bh_bit x 80 chunks = 1280 blocks, ~4 resident/CU + backfill
    gate_attn<<<dim3(1280), dim3(128), 0, stream>>>(u, q, (const short*)d_ws, out);
}

// Round 19
// 46.896 us; speedup vs baseline: 1.4111x; 1.4055x over previous
//
#include <hip/hip_runtime.h>
#include <hip/hip_bf16.h>

// (B,L,H,E,D) = (2,2048,8,64,64); E==D==64.
namespace {
constexpr int Lc = 2048, Hc = 8;
constexpr int RS = Hc * 64;          // floats between consecutive l (=512)
constexpr int NKT = 32;              // 2048/64 kt tiles
constexpr int TILE_BYTES = 16384;    // K frags 8KB + V frags 8KB per (bh,kt)
constexpr int OUT4 = 2 * Lc * Hc * 64 / 4;            // 524288 float4s
constexpr size_t POFF = (size_t)16 * NKT * TILE_BYTES; // partials after frag tiles (8 MiB)
}

typedef __attribute__((ext_vector_type(8))) short bf16x8;
typedef __attribute__((ext_vector_type(16))) float f32x16;
typedef unsigned int u32;
typedef __attribute__((ext_vector_type(4))) u32 u32x4;

__device__ __forceinline__ short f2bf(float x) {
    return (short)__builtin_bit_cast(unsigned short, __float2bfloat16(x));
}

#define MFMA32(a, b, c) __builtin_amdgcn_mfma_f32_32x32x16_bf16((a), (b), (c), 0, 0, 0)

#define GLL16(gp, lp) __builtin_amdgcn_global_load_lds( \
    (const __attribute__((address_space(1))) unsigned int*)(gp), \
    (__attribute__((address_space(3))) unsigned int*)(lp), 16, 0, 0)

// ------------- prep: f32 K,V -> bf16 32x32x16-fragment-ordered tiles in ws -------------
// (unchanged — validated rounds 7-18)
__global__ __launch_bounds__(256)
void prep_kv(const float* __restrict__ kg, const float* __restrict__ vg,
             short* __restrict__ ws)
{
    const int kt = blockIdx.x, bh = blockIdx.y;
    const int b = bh >> 3, h = bh & 7;
    const size_t base = ((size_t)b * Lc * Hc + h) * 64;
    char* tile = (char*)ws + (size_t)(bh * NKT + kt) * TILE_BYTES;
    const int tid = threadIdx.x;

    {   // K A-frags
        const int c = tid & 7, e0 = c * 8;
        #pragma unroll
        for (int p = 0; p < 2; ++p) {
            const int s = (tid >> 3) + 32 * p;
            const float* src = kg + base + (size_t)(kt * 64 + s) * RS + e0;
            float4 x0 = *(const float4*)src;
            float4 x1 = *(const float4*)(src + 4);
            bf16x8 w = { f2bf(x0.x), f2bf(x0.y), f2bf(x0.z), f2bf(x0.w),
                         f2bf(x1.x), f2bf(x1.y), f2bf(x1.z), f2bf(x1.w) };
            const int lane = (c & 1) * 32 + (s & 31);
            const int byte = ((s >> 5) * 4 + (c >> 1)) * 1024 + lane * 16;
            *(bf16x8*)(tile + byte) = w;
        }
    }
    {   // V B-frags
        const int d = tid & 63;
        #pragma unroll
        for (int p = 0; p < 2; ++p) {
            const int sblk = (tid >> 6) + 4 * p;
            const int s0 = sblk * 8;
            float xv[8];
            #pragma unroll
            for (int j = 0; j < 8; ++j)
                xv[j] = vg[base + (size_t)(kt * 64 + s0 + j) * RS + d];
            bf16x8 w = { f2bf(xv[0]), f2bf(xv[1]), f2bf(xv[2]), f2bf(xv[3]),
                         f2bf(xv[4]), f2bf(xv[5]), f2bf(xv[6]), f2bf(xv[7]) };
            const int lane = (sblk & 1) * 32 + (d & 31);
            const int byte = 8192 + ((d >> 5) * 4 + (sblk >> 1)) * 1024 + lane * 16;
            *(bf16x8*)(tile + byte) = w;
        }
    }
}

// ---- attention: 2-wave blocks (qs split), fixed 4 chunks/strip (<=8 tiles each),
// ---- K+V staged LDS, XCD-local ws; DIRECT f32 partial stores (no atomics).
__global__ __launch_bounds__(128, 2)
void gate_attn(const float* __restrict__ qg, const short* __restrict__ ws,
               float* __restrict__ partials)
{
    __shared__ __align__(16) char lds[2][TILE_BYTES];   // 32KB double-buffer

    const int tid = threadIdx.x;
    const int qs = tid >> 6, lane = tid & 63;
    const int col = lane & 31, hi = lane >> 5;

    // block -> (xcd-local bh, strip desc, chunk 0..3)
    const int i = (int)blockIdx.x;
    const int xcd = i & 7;
    const int r2 = i >> 3;                // 0..255
    const int bh_bit = r2 & 1;
    const int r3 = r2 >> 1;               // 0..127
    const int strip = 31 - (r3 >> 2);     // heavy strips first
    const int c = r3 & 3;
    const int bh = 2 * xcd + bh_bit;

    const int k0 = c * 8;
    if (k0 > strip) return;               // inactive chunk (slot never read)
    const int k1 = min(k0 + 7, strip);

    const int b = bh >> 3, h = bh & 7;
    const size_t base = ((size_t)b * Lc * Hc + h) * 64;
    const char* wsbh = (const char*)ws + (size_t)bh * NKT * TILE_BYTES;

    const int qw = strip * 64 + qs * 32;
    const int qg_l = qw + col;

    // ---- Q B-fragments (validated) ----
    bf16x8 qf[4];
    #pragma unroll
    for (int es = 0; es < 4; ++es) {
        const float* p = qg + base + (size_t)(qw + col) * RS + es * 16 + hi * 8;
        float4 a = *(const float4*)p;
        float4 c2 = *(const float4*)(p + 4);
        qf[es] = (bf16x8){ f2bf(a.x),  f2bf(a.y),  f2bf(a.z),  f2bf(a.w),
                           f2bf(c2.x), f2bf(c2.y), f2bf(c2.z), f2bf(c2.w) };
    }

    auto STAGE = [&](int t, int buf) {    // full 16KB tile, 8 GLL16/thread
        const char* src = wsbh + (size_t)t * TILE_BYTES + tid * 16;
        char* dst = &lds[buf][0] + tid * 16;
        #pragma unroll
        for (int ii = 0; ii < 8; ++ii)
            GLL16(src + ii * 2048, dst + ii * 2048);
    };

    f32x16 oacc[2];
    #pragma unroll
    for (int r = 0; r < 16; ++r) { oacc[0][r] = 0.f; oacc[1][r] = 0.f; }

    STAGE(k0, 0);
    __syncthreads();

    for (int kt = k0; kt <= k1; ++kt) {
        const int buf = (kt - k0) & 1;
        if (kt < k1) STAGE(kt + 1, buf ^ 1);
        const char* kb = &lds[buf][0];

        // ---- swapped QK^T (validated r7/r9 path) ----
        f32x16 sacc[2];
        #pragma unroll
        for (int r = 0; r < 16; ++r) { sacc[0][r] = 0.f; sacc[1][r] = 0.f; }
        __builtin_amdgcn_s_setprio(1);
        #pragma unroll
        for (int sb = 0; sb < 2; ++sb)
            #pragma unroll
            for (int es = 0; es < 4; ++es) {
                bf16x8 kf = *(const bf16x8*)(kb + (sb * 4 + es) * 1024 + lane * 16);
                sacc[sb] = MFMA32(kf, qf[es], sacc[sb]);
            }
        __builtin_amdgcn_s_setprio(0);

        // ---- relu^2 + mask; cvt_pk pack; permlane -> PA frags ----
        const bool dmask = (kt == strip);
        u32 pa[4][4];
        #pragma unroll
        for (int sb = 0; sb < 2; ++sb) {
            float pv[16];
            #pragma unroll
            for (int r = 0; r < 16; ++r) {
                float x2 = sacc[sb][r];
                x2 = (x2 > 0.f) ? x2 * x2 : 0.f;
                const int s_g = kt * 64 + sb * 32 + (r & 3) + 8 * (r >> 2) + 4 * hi;
                if (dmask && s_g > qg_l) x2 = 0.f;
                pv[r] = x2;
            }
            u32 W[8];
            #pragma unroll
            for (int t = 0; t < 8; ++t)
                asm("v_cvt_pk_bf16_f32 %0, %1, %2"
                    : "=v"(W[t]) : "v"(pv[2 * t]), "v"(pv[2 * t + 1]));
            asm volatile("v_permlane32_swap_b32 %0, %1" : "+v"(W[0]), "+v"(W[2]));
            asm volatile("v_permlane32_swap_b32 %0, %1" : "+v"(W[1]), "+v"(W[3]));
            asm volatile("v_permlane32_swap_b32 %0, %1" : "+v"(W[4]), "+v"(W[6]));
            asm volatile("v_permlane32_swap_b32 %0, %1" : "+v"(W[5]), "+v"(W[7]));
            pa[sb * 2 + 0][0] = W[0]; pa[sb * 2 + 0][1] = W[1];
            pa[sb * 2 + 0][2] = W[2]; pa[sb * 2 + 0][3] = W[3];
            pa[sb * 2 + 1][0] = W[4]; pa[sb * 2 + 1][1] = W[5];
            pa[sb * 2 + 1][2] = W[6]; pa[sb * 2 + 1][3] = W[7];
        }

        // ---- PV from LDS V-frags ----
        const char* vb = kb + 8192;
        __builtin_amdgcn_s_setprio(1);
        #pragma unroll
        for (int dh = 0; dh < 2; ++dh)
            #pragma unroll
            for (int ks = 0; ks < 4; ++ks) {
                bf16x8 vf = *(const bf16x8*)(vb + (dh * 4 + ks) * 1024 + lane * 16);
                u32x4 pw = { pa[ks][0], pa[ks][1], pa[ks][2], pa[ks][3] };
                oacc[dh] = MFMA32(__builtin_bit_cast(bf16x8, pw), vf, oacc[dh]);
            }
        __builtin_amdgcn_s_setprio(0);

        __syncthreads();
    }

    // ---- direct partial store: slot[bh][strip][c] is a 64x64 f32 tile ----
    float* slot = partials + ((size_t)(bh * NKT + strip) * 4 + c) * 4096;
    #pragma unroll
    for (int dh = 0; dh < 2; ++dh)
        #pragma unroll
        for (int r = 0; r < 16; ++r) {
            const int m = (r & 3) + 8 * (r >> 2) + 4 * hi;
            slot[(qs * 32 + m) * 64 + dh * 32 + col] = oacc[dh][r];
        }
}

// ---- reduce: out = u * sc * sum_c partials[bh][strip][c] ----
__global__ __launch_bounds__(256)
void reduce_gate(const float* __restrict__ ug, const float* __restrict__ partials,
                 float* __restrict__ outg)
{
    const int e = blockIdx.x * 256 + threadIdx.x;   // float4 index
    if (e >= OUT4) return;
    const int d4 = (e & 15) * 4;
    const int h  = (e >> 4) & 7;
    const int l  = (e >> 7) & 2047;
    const int b  = e >> 18;
    const int strip = l >> 6, row = l & 63;
    const int bh = b * 8 + h;
    const int nc = (strip + 8) >> 3;                // ceil((strip+1)/8) active chunks
    const float* slot0 = partials + ((size_t)(bh * NKT + strip) * 4) * 4096 + row * 64 + d4;
    float4 s = make_float4(0.f, 0.f, 0.f, 0.f);
    for (int c = 0; c < nc; ++c) {
        const float4 p = *(const float4*)(slot0 + (size_t)c * 4096);
        s.x += p.x; s.y += p.y; s.z += p.z; s.w += p.w;
    }
    const float sc = 1.0f / (64.0f * 2048.0f);      // exact pow2
    const float4 uu = ((const float4*)ug)[e];
    float4 o;
    o.x = uu.x * s.x * sc; o.y = uu.y * s.y * sc;
    o.z = uu.z * s.z * sc; o.w = uu.w * s.w * sc;
    ((float4*)outg)[e] = o;
}

extern "C" void kernel_launch(void* const* d_in, const int* in_sizes, int n_in,
                              void* d_out, int out_size, void* d_ws, size_t ws_size,
                              hipStream_t stream) {
    const float* u = (const float*)d_in[0];
    const float* q = (const float*)d_in[1];
    const float* k = (const float*)d_in[2];
    const float* v = (const float*)d_in[3];
    // d_in[4] (mask) is strict-upper-triangular; implemented analytically.
    float* out = (float*)d_out;

    short* ws = (short*)d_ws;                        // 8 MiB frag tiles
    float* partials = (float*)((char*)d_ws + POFF);  // 32 MiB partial tiles

    prep_kv<<<dim3(NKT, 16), dim3(256), 0, stream>>>(k, v, ws);
    // 8 xcd x 2 bh_bit x 32 strip x 4 chunk = 2048 blocks (768 exit immediately)
    gate_attn<<<dim3(2048), dim3(128), 0, stream>>>(q, (const short*)ws, partials);
    reduce_gate<<<dim3((OUT4 + 255) / 256), dim3(256), 0, stream>>>(u, partials, out);
}